// Round 7
// baseline (145.714 us; speedup 1.0000x reference)
//
#include <hip/hip_runtime.h>

// Batched tiny GRU: B=512, T=4096, C=hidden=4.
//
// R15: SCALAR v_fma_f32 gate math on the verified R11 structure.
// R14 post-mortem: dot2 was exec-null (busy/dual ~1070 vs 1030) + WRITE
// regression (92MB, partial-line evictions over slower emit cadence) ->
// 73us. Reverted. Remaining hypothesis for R11's 2110cy/dual wall:
// v_pk_fma_f32 is HALF-RATE on gfx950 (8cy wave64 - packed f32 saves
// instruction slots, not FLOP cycles; f64-pipe heritage). Consistent with
// R14's dot2-null and with exec ~= 96x8 + 36x16 + glue ~= wall.
// Test+win: all-scalar v_fma_f32 (definitively full-rate 2cy): 192 scalar
// FMA/dual = 384cy (vs possibly 768), no splats needed, issue count ~330
// stays under the wall. Predict 56 -> ~45-48us if half-rate; null if not.
// Structure IDENTICAL to R11 (verified): CHUNK=16, 1 wave/SIMD, 2 chains/
// lane statement-interleaved, native [b][c][t] loads/stores, peeled emit,
// group-aligned pre-sequence masking, exp2 scales folded into weights
// (R12/R14-verified), paired-rcp sigmoid/tanh (R11-verified).

#define TB 512
#define TT 4096
#define CHUNK 16
#define WARM 48
#define NCH (TT / CHUNK)  // 256 chunks/row; 128 per block-y, 2 per lane
#define L2E 1.4426950408889634f

__device__ __forceinline__ float fexp2(float x) { return __builtin_amdgcn_exp2f(x); }
__device__ __forceinline__ float frcp(float x)  { return __builtin_amdgcn_rcpf(x); }

__global__ __launch_bounds__(64, 1) void gru_scan(
    const float* __restrict__ x, const float* __restrict__ wih,
    const float* __restrict__ whh, const float* __restrict__ bih,
    const float* __restrict__ bhh, float* __restrict__ out) {
  const int lane = threadIdx.x;
  const int b = blockIdx.x;                  // batch row (uniform per block)
  const int chA = blockIdx.y * 128 + lane;   // chain A chunk
  const int t0A = chA * CHUNK;
  const int tbaseA = t0A - WARM;             // negative only for by==0 lane<3
  const int t0B = t0A + 64 * CHUNK;          // chain B = chunk chA+64
  const int tbaseB = t0B - WARM;             // >= 976, never clamped/masked

  // Scalar weights, wave-uniform -> SGPR-resident (1 SGPR operand per
  // v_fma_f32 is legal). Gate rows g: 0-3 r, 4-7 z, 8-11 n (PyTorch).
  // exp2 scales folded: r,z rows & biases x -L2E; n rows & biases x -2L2E.
  float Wi[12][4], Wh[12][4];
  float brz[8], bxn[4], bhn[4];
#pragma unroll
  for (int g = 0; g < 12; ++g) {
    const float s = (g < 8) ? -L2E : (-2.0f * L2E);
#pragma unroll
    for (int c = 0; c < 4; ++c) {
      Wi[g][c] = wih[g * 4 + c] * s;
      Wh[g][c] = whh[g * 4 + c] * s;
    }
  }
#pragma unroll
  for (int g = 0; g < 8; ++g) brz[g] = (bih[g] + bhh[g]) * (-L2E);
#pragma unroll
  for (int j = 0; j < 4; ++j) {
    bxn[j] = bih[8 + j] * (-2.0f * L2E);  // n x-part bias
    bhn[j] = bhh[8 + j] * (-2.0f * L2E);  // n h-part bias (inside r*( ))
  }

  // Native-layout bases: scalar (uniform b) base + per-lane voffset.
  const float* xb0 = x + ((size_t)b * 4 + 0) * TT;
  const float* xb1 = x + ((size_t)b * 4 + 1) * TT;
  const float* xb2 = x + ((size_t)b * 4 + 2) * TT;
  const float* xb3 = x + ((size_t)b * 4 + 3) * TT;
  float* oA0 = out + ((size_t)b * 4 + 0) * TT + t0A;
  float* oA1 = out + ((size_t)b * 4 + 1) * TT + t0A;
  float* oA2 = out + ((size_t)b * 4 + 2) * TT + t0A;
  float* oA3 = out + ((size_t)b * 4 + 3) * TT + t0A;
  float* oB0 = oA0 + 64 * CHUNK;
  float* oB1 = oA1 + 64 * CHUNK;
  float* oB2 = oA2 + 64 * CHUNK;
  float* oB3 = oA3 + 64 * CHUNK;

  float hA0 = 0.f, hA1 = 0.f, hA2 = 0.f, hA3 = 0.f;
  float hB0 = 0.f, hB1 = 0.f, hB2 = 0.f, hB3 = 0.f;
  float4 XAa[4], XBa[4];  // chain A X double buffers, [channel]
  float4 XAb[4], XBb[4];  // chain B X double buffers

  auto LD = [&](float4 (&Xa)[4], float4 (&Xb)[4], int g) {
    int ta = tbaseA + 4 * g;
    ta = ta < 0 ? 0 : ta;  // clamp: pre-sequence reads are discarded
    const int tb = tbaseB + 4 * g;
    Xa[0] = *(const float4*)(xb0 + ta);
    Xb[0] = *(const float4*)(xb0 + tb);
    Xa[1] = *(const float4*)(xb1 + ta);
    Xb[1] = *(const float4*)(xb1 + tb);
    Xa[2] = *(const float4*)(xb2 + ta);
    Xb[2] = *(const float4*)(xb2 + tb);
    Xa[3] = *(const float4*)(xb3 + ta);
    Xb[3] = *(const float4*)(xb3 + tb);
  };

  // One GRU step on BOTH chains, all-scalar FMA, statement-interleaved.
  // 16 independent 8-deep fma chains (r,z) + 16 independent 4-deep (n)
  // per dual-step -> plenty of ILP without any hoisted arrays.
  auto STEP2 = [&](float xa0, float xa1, float xa2, float xa3,
                   float xb0v, float xb1v, float xb2v, float xb3v) {
    // r,z gates (0..7): a = brz + Wi.x + Wh.h, 8 chained scalar fma.
    float aA[8], aB[8];
#pragma unroll
    for (int g = 0; g < 8; ++g) {
      float tA = fmaf(Wi[g][0], xa0, brz[g]);
      float tB = fmaf(Wi[g][0], xb0v, brz[g]);
      tA = fmaf(Wi[g][1], xa1, tA);
      tB = fmaf(Wi[g][1], xb1v, tB);
      tA = fmaf(Wi[g][2], xa2, tA);
      tB = fmaf(Wi[g][2], xb2v, tB);
      tA = fmaf(Wi[g][3], xa3, tA);
      tB = fmaf(Wi[g][3], xb3v, tB);
      tA = fmaf(Wh[g][0], hA0, tA);
      tB = fmaf(Wh[g][0], hB0, tB);
      tA = fmaf(Wh[g][1], hA1, tA);
      tB = fmaf(Wh[g][1], hB1, tB);
      tA = fmaf(Wh[g][2], hA2, tA);
      tB = fmaf(Wh[g][2], hB2, tB);
      aA[g] = fmaf(Wh[g][3], hA3, tA);
      aB[g] = fmaf(Wh[g][3], hB3, tB);
    }
    // n gates (8..11): x-part and h-part separate (r gates the h-part).
    float xnA[4], xnB[4], vhA[4], vhB[4];
#pragma unroll
    for (int j = 0; j < 4; ++j) {
      const int g = 8 + j;
      float tA = fmaf(Wi[g][0], xa0, bxn[j]);
      float tB = fmaf(Wi[g][0], xb0v, bxn[j]);
      tA = fmaf(Wi[g][1], xa1, tA);
      tB = fmaf(Wi[g][1], xb1v, tB);
      tA = fmaf(Wi[g][2], xa2, tA);
      tB = fmaf(Wi[g][2], xb2v, tB);
      xnA[j] = fmaf(Wi[g][3], xa3, tA);
      xnB[j] = fmaf(Wi[g][3], xb3v, tB);
      float uA = fmaf(Wh[g][0], hA0, bhn[j]);
      float uB = fmaf(Wh[g][0], hB0, bhn[j]);
      uA = fmaf(Wh[g][1], hA1, uA);
      uB = fmaf(Wh[g][1], hB1, uB);
      uA = fmaf(Wh[g][2], hA2, uA);
      uB = fmaf(Wh[g][2], hB2, uB);
      vhA[j] = fmaf(Wh[g][3], hA3, uA);
      vhB[j] = fmaf(Wh[g][3], hB3, uB);
    }
    // 8 sigmoids per chain (args pre-scaled by -L2E), paired rcp.
    // sg[0..3] = r gates, sg[4..7] = z gates.
    float sgA[8], sgB[8];
#pragma unroll
    for (int p = 0; p < 4; ++p) {
      float eA0 = fexp2(aA[2 * p]);
      float eB0 = fexp2(aB[2 * p]);
      float eA1 = fexp2(aA[2 * p + 1]);
      float eB1 = fexp2(aB[2 * p + 1]);
      float dA0 = 1.0f + eA0, dA1 = 1.0f + eA1;
      float dB0 = 1.0f + eB0, dB1 = 1.0f + eB1;
      float RA = frcp(dA0 * dA1);
      float RB = frcp(dB0 * dB1);
      sgA[2 * p] = dA1 * RA;
      sgA[2 * p + 1] = dA0 * RA;
      sgB[2 * p] = dB1 * RB;
      sgB[2 * p + 1] = dB0 * RB;
    }
    // 4 tanh per chain: y = xn + r*vh (already -2L2E scaled), paired rcp
    // with the 2x folded into R: n = fma(d_other, R, -1).
    float yA0 = fmaf(sgA[0], vhA[0], xnA[0]);
    float yB0 = fmaf(sgB[0], vhB[0], xnB[0]);
    float yA1 = fmaf(sgA[1], vhA[1], xnA[1]);
    float yB1 = fmaf(sgB[1], vhB[1], xnB[1]);
    float yA2 = fmaf(sgA[2], vhA[2], xnA[2]);
    float yB2 = fmaf(sgB[2], vhB[2], xnB[2]);
    float yA3 = fmaf(sgA[3], vhA[3], xnA[3]);
    float yB3 = fmaf(sgB[3], vhB[3], xnB[3]);
    float fA0 = fexp2(yA0), fA1 = fexp2(yA1), fA2 = fexp2(yA2), fA3 = fexp2(yA3);
    float fB0 = fexp2(yB0), fB1 = fexp2(yB1), fB2 = fexp2(yB2), fB3 = fexp2(yB3);
    float daA = 1.0f + fA0, dbA = 1.0f + fA1, dcA = 1.0f + fA2, ddA = 1.0f + fA3;
    float daB = 1.0f + fB0, dbB = 1.0f + fB1, dcB = 1.0f + fB2, ddB = 1.0f + fB3;
    float RaA = 2.0f * frcp(daA * dbA), RbA = 2.0f * frcp(dcA * ddA);
    float RaB = 2.0f * frcp(daB * dbB), RbB = 2.0f * frcp(dcB * ddB);
    float nA0 = fmaf(dbA, RaA, -1.0f);  // tanh = 2/(1+e^-2y) - 1
    float nA1 = fmaf(daA, RaA, -1.0f);
    float nA2 = fmaf(ddA, RbA, -1.0f);
    float nA3 = fmaf(dcA, RbA, -1.0f);
    float nB0 = fmaf(dbB, RaB, -1.0f);
    float nB1 = fmaf(daB, RaB, -1.0f);
    float nB2 = fmaf(ddB, RbB, -1.0f);
    float nB3 = fmaf(dcB, RbB, -1.0f);
    // h' = n + z*(h - n); z = sg[4..7].
    hA0 = fmaf(sgA[4], hA0 - nA0, nA0);
    hB0 = fmaf(sgB[4], hB0 - nB0, nB0);
    hA1 = fmaf(sgA[5], hA1 - nA1, nA1);
    hB1 = fmaf(sgB[5], hB1 - nB1, nB1);
    hA2 = fmaf(sgA[6], hA2 - nA2, nA2);
    hB2 = fmaf(sgB[6], hB2 - nB2, nB2);
    hA3 = fmaf(sgA[7], hA3 - nA3, nA3);
    hB3 = fmaf(sgB[7], hB3 - nB3, nB3);
  };

  // Warm group: 4 dual-steps + group-aligned pre-sequence mask on chain A
  // only (chain B has t0 >= 1024 >= WARM, never pre-sequence).
  auto RUN4G2 = [&](float4 (&Xa)[4], float4 (&Xb)[4], int g) {
    STEP2(Xa[0].x, Xa[1].x, Xa[2].x, Xa[3].x,
          Xb[0].x, Xb[1].x, Xb[2].x, Xb[3].x);
    STEP2(Xa[0].y, Xa[1].y, Xa[2].y, Xa[3].y,
          Xb[0].y, Xb[1].y, Xb[2].y, Xb[3].y);
    STEP2(Xa[0].z, Xa[1].z, Xa[2].z, Xa[3].z,
          Xb[0].z, Xb[1].z, Xb[2].z, Xb[3].z);
    STEP2(Xa[0].w, Xa[1].w, Xa[2].w, Xa[3].w,
          Xb[0].w, Xb[1].w, Xb[2].w, Xb[3].w);
    if (tbaseA + 4 * g < 0) { hA0 = 0.f; hA1 = 0.f; hA2 = 0.f; hA3 = 0.f; }
  };

  // Emit group: 4 dual-steps + one float4 store per channel per chain.
  auto EMIT2 = [&](float4 (&Xa)[4], float4 (&Xb)[4], int off) {
    float oa0[4], oa1[4], oa2[4], oa3[4];
    float ob0[4], ob1[4], ob2[4], ob3[4];
    STEP2(Xa[0].x, Xa[1].x, Xa[2].x, Xa[3].x,
          Xb[0].x, Xb[1].x, Xb[2].x, Xb[3].x);
    oa0[0] = hA0; oa1[0] = hA1; oa2[0] = hA2; oa3[0] = hA3;
    ob0[0] = hB0; ob1[0] = hB1; ob2[0] = hB2; ob3[0] = hB3;
    STEP2(Xa[0].y, Xa[1].y, Xa[2].y, Xa[3].y,
          Xb[0].y, Xb[1].y, Xb[2].y, Xb[3].y);
    oa0[1] = hA0; oa1[1] = hA1; oa2[1] = hA2; oa3[1] = hA3;
    ob0[1] = hB0; ob1[1] = hB1; ob2[1] = hB2; ob3[1] = hB3;
    STEP2(Xa[0].z, Xa[1].z, Xa[2].z, Xa[3].z,
          Xb[0].z, Xb[1].z, Xb[2].z, Xb[3].z);
    oa0[2] = hA0; oa1[2] = hA1; oa2[2] = hA2; oa3[2] = hA3;
    ob0[2] = hB0; ob1[2] = hB1; ob2[2] = hB2; ob3[2] = hB3;
    STEP2(Xa[0].w, Xa[1].w, Xa[2].w, Xa[3].w,
          Xb[0].w, Xb[1].w, Xb[2].w, Xb[3].w);
    oa0[3] = hA0; oa1[3] = hA1; oa2[3] = hA2; oa3[3] = hA3;
    ob0[3] = hB0; ob1[3] = hB1; ob2[3] = hB2; ob3[3] = hB3;
    *(float4*)(oA0 + off) = make_float4(oa0[0], oa0[1], oa0[2], oa0[3]);
    *(float4*)(oB0 + off) = make_float4(ob0[0], ob0[1], ob0[2], ob0[3]);
    *(float4*)(oA1 + off) = make_float4(oa1[0], oa1[1], oa1[2], oa1[3]);
    *(float4*)(oB1 + off) = make_float4(ob1[0], ob1[1], ob1[2], ob1[3]);
    *(float4*)(oA2 + off) = make_float4(oa2[0], oa2[1], oa2[2], oa2[3]);
    *(float4*)(oB2 + off) = make_float4(ob2[0], ob2[1], ob2[2], ob2[3]);
    *(float4*)(oA3 + off) = make_float4(oa3[0], oa3[1], oa3[2], oa3[3]);
    *(float4*)(oB3 + off) = make_float4(ob3[0], ob3[1], ob3[2], ob3[3]);
  };

  // 16 groups total: 12 warm (0..11), 4 emit (12..15). Uniform trip count
  // across all lanes and both chains -> wave stays lockstep.
  LD(XAa, XAb, 0);
#pragma unroll 1  // keep rolled
  for (int g = 0; g < 12; g += 2) {
    LD(XBa, XBb, g + 1);
    RUN4G2(XAa, XAb, g);
    LD(XAa, XAb, g + 2);  // g+2 reaches 12 = first emit group
    RUN4G2(XBa, XBb, g + 1);
  }
  // Emit phase: XAa/XAb hold group 12. Peeled; last load is group 15
  // (chain B max t = 4095 -> no prefetch past end).
  LD(XBa, XBb, 13);
  EMIT2(XAa, XAb, 0);
  LD(XAa, XAb, 14);
  EMIT2(XBa, XBb, 4);
  LD(XBa, XBb, 15);
  EMIT2(XAa, XAb, 8);
  EMIT2(XBa, XBb, 12);
}

extern "C" void kernel_launch(void* const* d_in, const int* in_sizes, int n_in,
                              void* d_out, int out_size, void* d_ws, size_t ws_size,
                              hipStream_t stream) {
  const float* x   = (const float*)d_in[0];
  const float* wih = (const float*)d_in[1];
  const float* whh = (const float*)d_in[2];
  const float* bih = (const float*)d_in[3];
  const float* bhh = (const float*)d_in[4];
  float* out = (float*)d_out;
  (void)d_ws; (void)ws_size;

  gru_scan<<<dim3(TB, NCH / 128), 64, 0, stream>>>(x, wih, whh, bih, bhh, out);
}

// Round 8
// 127.940 us; speedup vs baseline: 1.1389x; 1.1389x over previous
//
#include <hip/hip_runtime.h>

// Batched tiny GRU: B=512, T=4096, C=hidden=4.
//
// R16: the clean 2-waves/SIMD experiment — R11 footprint, 1 chain/thread.
// R15 post-mortem: scalar FMA raised busy/dual 1030->1330 (2x FMA instrs +
// SGPR-operand movs) -> 80us. pk_fma is the right encoding (R14+R15).
// R11's wall = 2.05 x busy at 1 wave/SIMD. Open question: issue-cadence cap
// (wave issues 1 VALU / 4cy -> 50% ceiling per wave) vs unfillable dep
// stall. R10 seemed to refute "add a wave" but was CONFOUNDED: its mapping
// fetched 50MB vs R11's 17MB. This round: SAME block footprint as R11 (one
// b-row, 128 consecutive chunks per block) but 128-thread blocks, one chain
// per thread -> 2048 waves = 2/SIMD, same total work, same 8 streams/CU.
// VGPR ~halves (single chain) so 2 waves/SIMD fits easily.
// Predict: cadence-cap true -> 56 -> ~32-42us, VALUBusy 70-95%.
//          dep-stall true  -> null (~56-69us, busy ~50%) -> R11 is floor.
// Math: R11/R12-verified packed pk_fma gates, folded exp2 scales, paired
// rcp. Group-aligned pre-sequence masking (exact). Peeled emit.

#define TB 512
#define TT 4096
#define CHUNK 16
#define WARM 48
#define NCH (TT / CHUNK)  // 256 chunks/row; 128 per block-y, 1 per thread
#define L2E 1.4426950408889634f

typedef float v2f __attribute__((ext_vector_type(2)));

__device__ __forceinline__ float fexp2(float x) { return __builtin_amdgcn_exp2f(x); }
__device__ __forceinline__ float frcp(float x)  { return __builtin_amdgcn_rcpf(x); }
__device__ __forceinline__ v2f   splat2(float s) { v2f v; v.x = s; v.y = s; return v; }
__device__ __forceinline__ v2f   pfma(v2f a, v2f b, v2f c) {
  return __builtin_elementwise_fma(a, b, c);
}

__global__ __launch_bounds__(128, 2) void gru_scan(
    const float* __restrict__ x, const float* __restrict__ wih,
    const float* __restrict__ whh, const float* __restrict__ bih,
    const float* __restrict__ bhh, float* __restrict__ out) {
  const int tid = threadIdx.x;
  const int b = blockIdx.x;                  // batch row (uniform per block)
  const int ch = blockIdx.y * 128 + tid;     // one chain per thread
  const int t0 = ch * CHUNK;
  const int tbase = t0 - WARM;               // negative only for y==0 tid<3

  // Gate-pair packed weights; wave-uniform -> SGPR-resident.
  // Pairs p: 0,1 = r gates; 2,3 = z gates; 4,5 = n gates (PyTorch rows).
  // exp2 scales folded (R12-verified): r,z x -L2E; n x -2L2E.
  v2f Wi2[6][4], Wh2[6][4], bg2[6], bnh2[2];
#pragma unroll
  for (int p = 0; p < 6; ++p) {
    const float s = (p < 4) ? -L2E : (-2.0f * L2E);
#pragma unroll
    for (int c = 0; c < 4; ++c) {
      Wi2[p][c].x = wih[(2 * p) * 4 + c] * s;
      Wi2[p][c].y = wih[(2 * p + 1) * 4 + c] * s;
      Wh2[p][c].x = whh[(2 * p) * 4 + c] * s;
      Wh2[p][c].y = whh[(2 * p + 1) * 4 + c] * s;
    }
    if (p < 4) {  // r,z: fold both biases (scaled)
      bg2[p].x = (bih[2 * p] + bhh[2 * p]) * s;
      bg2[p].y = (bih[2 * p + 1] + bhh[2 * p + 1]) * s;
    } else {      // n: x-part bias only (scaled); h-part stays inside r*( )
      bg2[p].x = bih[2 * p] * s;
      bg2[p].y = bih[2 * p + 1] * s;
    }
  }
#pragma unroll
  for (int q = 0; q < 2; ++q) {
    bnh2[q].x = bhh[8 + 2 * q] * (-2.0f * L2E);
    bnh2[q].y = bhh[8 + 2 * q + 1] * (-2.0f * L2E);
  }

  // Native-layout bases: scalar (uniform b) base + per-thread voffset.
  const float* xb0 = x + ((size_t)b * 4 + 0) * TT;
  const float* xb1 = x + ((size_t)b * 4 + 1) * TT;
  const float* xb2 = x + ((size_t)b * 4 + 2) * TT;
  const float* xb3 = x + ((size_t)b * 4 + 3) * TT;
  float* o0 = out + ((size_t)b * 4 + 0) * TT + t0;
  float* o1 = out + ((size_t)b * 4 + 1) * TT + t0;
  float* o2 = out + ((size_t)b * 4 + 2) * TT + t0;
  float* o3 = out + ((size_t)b * 4 + 3) * TT + t0;

  float h0 = 0.f, h1 = 0.f, h2 = 0.f, h3 = 0.f;
  float4 XA[4], XB[4];  // X double buffers, [channel]

  auto LD = [&](float4 (&X)[4], int g) {
    int t = tbase + 4 * g;
    t = t < 0 ? 0 : t;  // clamp: pre-sequence reads are discarded
    X[0] = *(const float4*)(xb0 + t);
    X[1] = *(const float4*)(xb1 + t);
    X[2] = *(const float4*)(xb2 + t);
    X[3] = *(const float4*)(xb3 + t);
  };

  // One GRU step, gates packed pairwise (48 pk_fma), folded exp2 scales,
  // paired-rcp sigmoid/tanh. Verified math (R11 structure + R12 folding).
  auto STEP = [&](float xv0, float xv1, float xv2, float xv3) {
    v2f xs0 = splat2(xv0), xs1 = splat2(xv1), xs2 = splat2(xv2),
        xs3 = splat2(xv3);
    v2f hs0 = splat2(h0), hs1 = splat2(h1), hs2 = splat2(h2), hs3 = splat2(h3);
    v2f a[6];
#pragma unroll
    for (int p = 0; p < 6; ++p) {
      v2f s = pfma(Wi2[p][0], xs0, bg2[p]);
      s = pfma(Wi2[p][1], xs1, s);
      s = pfma(Wi2[p][2], xs2, s);
      a[p] = pfma(Wi2[p][3], xs3, s);
    }
#pragma unroll
    for (int p = 0; p < 4; ++p) {  // r,z gates take h directly
      v2f s = pfma(Wh2[p][0], hs0, a[p]);
      s = pfma(Wh2[p][1], hs1, s);
      s = pfma(Wh2[p][2], hs2, s);
      a[p] = pfma(Wh2[p][3], hs3, s);
    }
    v2f vh[2];
#pragma unroll
    for (int q = 0; q < 2; ++q) {  // n-gate h-part (kept separate for r*( ))
      v2f s = pfma(Wh2[4 + q][0], hs0, bnh2[q]);
      s = pfma(Wh2[4 + q][1], hs1, s);
      s = pfma(Wh2[4 + q][2], hs2, s);
      vh[q] = pfma(Wh2[4 + q][3], hs3, s);
    }
    // 8 sigmoids (args pre-scaled by -L2E), paired rcp.
    float sg[8];
#pragma unroll
    for (int p = 0; p < 4; ++p) {
      float e0 = fexp2(a[p].x);
      float e1 = fexp2(a[p].y);
      float d0 = 1.0f + e0, d1 = 1.0f + e1;
      float R = frcp(d0 * d1);
      sg[2 * p] = d1 * R;
      sg[2 * p + 1] = d0 * R;
    }
    // 4 tanh: y already -2L2E scaled; paired rcp with 2x folded into R.
    float y0 = fmaf(sg[0], vh[0].x, a[4].x);
    float y1 = fmaf(sg[1], vh[0].y, a[4].y);
    float y2 = fmaf(sg[2], vh[1].x, a[5].x);
    float y3 = fmaf(sg[3], vh[1].y, a[5].y);
    float f0 = fexp2(y0), f1 = fexp2(y1), f2 = fexp2(y2), f3 = fexp2(y3);
    float da = 1.0f + f0, db = 1.0f + f1, dc = 1.0f + f2, dd = 1.0f + f3;
    float Ra = 2.0f * frcp(da * db), Rb = 2.0f * frcp(dc * dd);
    float n0 = fmaf(db, Ra, -1.0f);  // tanh = 2/(1+e^-2y) - 1
    float n1 = fmaf(da, Ra, -1.0f);
    float n2 = fmaf(dd, Rb, -1.0f);
    float n3 = fmaf(dc, Rb, -1.0f);
    h0 = fmaf(sg[4], h0 - n0, n0);
    h1 = fmaf(sg[5], h1 - n1, n1);
    h2 = fmaf(sg[6], h2 - n2, n2);
    h3 = fmaf(sg[7], h3 - n3, n3);
  };

  // Warm group: 4 steps + group-aligned pre-sequence mask (exact: h only
  // starts evolving at t=0; t0 and WARM are multiples of 4).
  auto RUN4G = [&](float4 (&X)[4], int g) {
    STEP(X[0].x, X[1].x, X[2].x, X[3].x);
    STEP(X[0].y, X[1].y, X[2].y, X[3].y);
    STEP(X[0].z, X[1].z, X[2].z, X[3].z);
    STEP(X[0].w, X[1].w, X[2].w, X[3].w);
    if (tbase + 4 * g < 0) { h0 = 0.f; h1 = 0.f; h2 = 0.f; h3 = 0.f; }
  };

  // Emit group: 4 steps + one float4 store per channel (literal off).
  auto EMIT4 = [&](float4 (&X)[4], int off) {
    float a0[4], a1[4], a2[4], a3[4];
    STEP(X[0].x, X[1].x, X[2].x, X[3].x);
    a0[0] = h0; a1[0] = h1; a2[0] = h2; a3[0] = h3;
    STEP(X[0].y, X[1].y, X[2].y, X[3].y);
    a0[1] = h0; a1[1] = h1; a2[1] = h2; a3[1] = h3;
    STEP(X[0].z, X[1].z, X[2].z, X[3].z);
    a0[2] = h0; a1[2] = h1; a2[2] = h2; a3[2] = h3;
    STEP(X[0].w, X[1].w, X[2].w, X[3].w);
    a0[3] = h0; a1[3] = h1; a2[3] = h2; a3[3] = h3;
    *(float4*)(o0 + off) = make_float4(a0[0], a0[1], a0[2], a0[3]);
    *(float4*)(o1 + off) = make_float4(a1[0], a1[1], a1[2], a1[3]);
    *(float4*)(o2 + off) = make_float4(a2[0], a2[1], a2[2], a2[3]);
    *(float4*)(o3 + off) = make_float4(a3[0], a3[1], a3[2], a3[3]);
  };

  // 16 groups total: 12 warm (0..11), 4 emit (12..15). Uniform trip count
  // across all threads -> waves stay lockstep.
  LD(XA, 0);
#pragma unroll 1  // keep rolled
  for (int g = 0; g < 12; g += 2) {
    LD(XB, g + 1);
    RUN4G(XA, g);
    LD(XA, g + 2);  // g+2 reaches 12 = first emit group
    RUN4G(XB, g + 1);
  }
  // Emit phase: XA holds group 12. Peeled; last load is group 15
  // (max t = t0+12+3 = 4095 -> no prefetch past end).
  LD(XB, 13);
  EMIT4(XA, 0);
  LD(XA, 14);
  EMIT4(XB, 4);
  LD(XB, 15);
  EMIT4(XA, 8);
  EMIT4(XB, 12);
}

extern "C" void kernel_launch(void* const* d_in, const int* in_sizes, int n_in,
                              void* d_out, int out_size, void* d_ws, size_t ws_size,
                              hipStream_t stream) {
  const float* x   = (const float*)d_in[0];
  const float* wih = (const float*)d_in[1];
  const float* whh = (const float*)d_in[2];
  const float* bih = (const float*)d_in[3];
  const float* bhh = (const float*)d_in[4];
  float* out = (float*)d_out;
  (void)d_ws; (void)ws_size;

  gru_scan<<<dim3(TB, NCH / 128), 128, 0, stream>>>(x, wih, whh, bih, bhh, out);
}